// Round 2
// 1138.179 us; speedup vs baseline: 1.1388x; 1.1388x over previous
//
#include <hip/hip_runtime.h>
#include <hip/hip_bf16.h>

#define NN 100000
#define NEDGE 1600000
#define NV (NN*32)
#define NEG 0.01f
#define EPS 1e-5f
#define NBLK 391            // ceil(NN/256)
#define STC 64              // stat copies (contention spread)
#define ST_STRIDE 4096      // STC * 64

// ---- static device arena (fp32) ----
#define OFF_STATS 0
#define STATS_F  (22*ST_STRIDE)
#define OFF_PA   STATS_F
#define OFF_PB   (OFF_PA + NV)
#define OFF_AGG  (OFF_PB + NV)
#define OFF_MSGB (OFF_AGG + NV)          // NV bf16 = NV/2 floats
#define OFF_RING (OFF_MSGB + NV/2)
#define OFF_WF   (OFF_RING + 4*NV)       // bf16 weight frags for final MLP (51200 shorts)
#define ARENA_F  (OFF_WF + 25600)

// weight-frag section bases in uint4 (16B) units
#define W0B 0
#define W1B 1024
#define W2B 5120
#define W3B 6144

__device__ __align__(16) float gA[ARENA_F];
__device__ int g_cnt[NN];
__device__ int g_rowptr[NN + 1];
__device__ int g_cur[NN];
__device__ int g_csr[NEDGE];
__device__ int g_bsum[NBLK];
__device__ int g_boff[NBLK];

__device__ __forceinline__ float lrelu(float v) { return v > 0.f ? v : v * NEG; }
__device__ __forceinline__ unsigned short f2b(float v) {
    __hip_bfloat16 b = __float2bfloat16(v);
    return *reinterpret_cast<unsigned short*>(&b);
}
__device__ __forceinline__ float b2f(unsigned short u) {
    __hip_bfloat16 b = *reinterpret_cast<__hip_bfloat16*>(&u);
    return __bfloat162float(b);
}

// ---------------- zero stats + counts ----------------
__global__ void k_zero_v17()
{
    int i = blockIdx.x * 256 + threadIdx.x;
    if (i < STATS_F) gA[i] = 0.f;
    if (i < NN) g_cnt[i] = 0;
}

// ---------------- CSR build ----------------
__global__ void k_count_v17(const int* __restrict__ col)
{
    int e = blockIdx.x * 256 + threadIdx.x;
    if (e < NEDGE) atomicAdd(&g_cnt[col[NEDGE + e]], 1);
}

__global__ __launch_bounds__(256) void k_bsum_v17()
{
    __shared__ int s[256];
    int i = blockIdx.x * 256 + threadIdx.x;
    int v = (i < NN) ? g_cnt[i] : 0;
    s[threadIdx.x] = v;
    __syncthreads();
    for (int off = 128; off > 0; off >>= 1) {
        if (threadIdx.x < off) s[threadIdx.x] += s[threadIdx.x + off];
        __syncthreads();
    }
    if (threadIdx.x == 0) g_bsum[blockIdx.x] = s[0];
}

__global__ __launch_bounds__(512) void k_bscan_v17()
{
    __shared__ int s[512];
    int t = threadIdx.x;
    int v = (t < NBLK) ? g_bsum[t] : 0;
    s[t] = v;
    __syncthreads();
    for (int off = 1; off < 512; off <<= 1) {
        int u = (t >= off) ? s[t - off] : 0;
        __syncthreads();
        s[t] += u;
        __syncthreads();
    }
    if (t < NBLK) g_boff[t] = s[t] - v;
    if (t == NBLK - 1) g_rowptr[NN] = s[t];
}

__global__ __launch_bounds__(256) void k_bexp_v17()
{
    __shared__ int s[256];
    int i = blockIdx.x * 256 + threadIdx.x;
    int t = threadIdx.x;
    int v = (i < NN) ? g_cnt[i] : 0;
    s[t] = v;
    __syncthreads();
    for (int off = 1; off < 256; off <<= 1) {
        int u = (t >= off) ? s[t - off] : 0;
        __syncthreads();
        s[t] += u;
        __syncthreads();
    }
    if (i < NN) {
        int p = g_boff[blockIdx.x] + s[t] - v;
        g_rowptr[i] = p;
        g_cur[i] = p;
    }
}

__global__ void k_fill_v17(const int* __restrict__ col)
{
    int e = blockIdx.x * 256 + threadIdx.x;
    if (e >= NEDGE) return;
    int s = col[e];
    int d = col[NEDGE + e];
    int pos = atomicAdd(&g_cur[d], 1);
    g_csr[pos] = s;
}

// ---------------- init layer 0: PA = x*Wi0 + bi0, stats ----------------
__global__ void k_init0_v17(const float* __restrict__ x, const float* __restrict__ Wi0,
                            const float* __restrict__ bi0)
{
    int j = threadIdx.x & 31, ns = threadIdx.x >> 5;
    float w = Wi0[j];
    float bb = bi0[j];
    __shared__ float red[64];
    if (threadIdx.x < 64) red[threadIdx.x] = 0.f;
    __syncthreads();
    float s1 = 0.f, s2 = 0.f;
    for (int t = blockIdx.x; t < NN / 8; t += gridDim.x) {
        int n = t * 8 + ns;
        float v = x[n] * w + bb;
        gA[OFF_PA + n * 32 + j] = v;
        s1 += v; s2 += v * v;
    }
    atomicAdd(&red[j], s1);
    atomicAdd(&red[j + 32], s2);
    __syncthreads();
    if (threadIdx.x < 64)
        atomicAdd(&gA[OFF_STATS + (blockIdx.x & (STC - 1)) * 64 + threadIdx.x], red[threadIdx.x]);
}

// ------- BN+LReLU (+resid) (+feats store) (+fused next 32x32 linear + stats) -------
__global__ void k_nl_v17(int off_in, int off_out, int out_msg, int st_in,
                         const float* __restrict__ gamma, const float* __restrict__ beta,
                         int off_resid, int off_feats,
                         const float* __restrict__ Wn, const float* __restrict__ bn,
                         int st_out)
{
    int j = threadIdx.x & 31, ns = threadIdx.x >> 5;
    __shared__ float sstat[64];
    __shared__ float red[64];
    if (threadIdx.x < 64) {
        red[threadIdx.x] = 0.f;
        float acc = 0.f;
        int base = st_in + threadIdx.x;
        #pragma unroll 8
        for (int c = 0; c < STC; ++c) acc += gA[base + c * 64];
        sstat[threadIdx.x] = acc;
    }
    __syncthreads();
    float mean = sstat[j] * (1.f / NN);
    float var  = sstat[32 + j] * (1.f / NN) - mean * mean;
    float scale = gamma[j] * rsqrtf(var + EPS);
    float shift = beta[j] - mean * scale;

    float wc[32]; float bb = 0.f;
    if (Wn) {
        #pragma unroll
        for (int k = 0; k < 32; ++k) wc[k] = Wn[k * 32 + j];
        bb = bn[j];
    }
    unsigned short* mb = (unsigned short*)(gA + OFF_MSGB);
    __shared__ float sH[8][32];
    float s1 = 0.f, s2 = 0.f;
    for (int t = blockIdx.x; t < NN / 8; t += gridDim.x) {
        int n = t * 8 + ns;
        float v = gA[off_in + n * 32 + j];
        v = lrelu(scale * v + shift);
        if (off_resid >= 0) v += gA[off_resid + n * 32 + j];
        if (off_feats >= 0) gA[off_feats + n * 32 + j] = v;
        if (Wn) {
            sH[ns][j] = v;
            __syncthreads();
            float acc = bb;
            #pragma unroll
            for (int k = 0; k < 32; k += 4) {
                float4 h4 = *(const float4*)&sH[ns][k];
                acc += h4.x * wc[k] + h4.y * wc[k + 1] + h4.z * wc[k + 2] + h4.w * wc[k + 3];
            }
            if (out_msg) mb[n * 32 + j] = f2b(acc);
            else gA[off_out + n * 32 + j] = acc;
            s1 += acc; s2 += acc * acc;
            __syncthreads();
        }
    }
    if (Wn) {
        atomicAdd(&red[j], s1);
        atomicAdd(&red[j + 32], s2);
        __syncthreads();
        if (threadIdx.x < 64)
            atomicAdd(&gA[st_out + (blockIdx.x & (STC - 1)) * 64 + threadIdx.x], red[threadIdx.x]);
    }
}

// ---------------- CSR gather with fused msg BN+LReLU (bf16 pre-acts), 4-edge unroll ----------------
__global__ __launch_bounds__(256) void k_gather_v17(int st,
                                                    const float* __restrict__ gm,
                                                    const float* __restrict__ bem)
{
    __shared__ float sstat[64];
    __shared__ float sc[32], sh[32];
    int tid = threadIdx.x;
    if (tid < 64) {
        float acc = 0.f;
        int base = st + tid;
        #pragma unroll 8
        for (int c = 0; c < STC; ++c) acc += gA[base + c * 64];
        sstat[tid] = acc;
    }
    __syncthreads();
    if (tid < 32) {
        float mean = sstat[tid] * (1.f / NN);
        float var  = sstat[32 + tid] * (1.f / NN) - mean * mean;
        float s = gm[tid] * rsqrtf(var + EPS);
        sc[tid] = s;
        sh[tid] = bem[tid] - mean * s;
    }
    __syncthreads();
    int n = blockIdx.x * 32 + (tid >> 3);
    int g = tid & 7;
    int e0 = g_rowptr[n], e1 = g_rowptr[n + 1];
    const unsigned short* mb = (const unsigned short*)(gA + OFF_MSGB);
    float c0 = sc[g*4], c1 = sc[g*4+1], c2 = sc[g*4+2], c3 = sc[g*4+3];
    float h0 = sh[g*4], h1 = sh[g*4+1], h2 = sh[g*4+2], h3 = sh[g*4+3];
    float a0 = 0.f, a1 = 0.f, a2 = 0.f, a3 = 0.f;
    int e = e0;
    for (; e + 3 < e1; e += 4) {
        int s0 = g_csr[e];
        int s1 = g_csr[e + 1];
        int s2 = g_csr[e + 2];
        int s3 = g_csr[e + 3];
        ushort4 m0 = *(const ushort4*)(mb + s0 * 32 + g * 4);
        ushort4 m1 = *(const ushort4*)(mb + s1 * 32 + g * 4);
        ushort4 m2 = *(const ushort4*)(mb + s2 * 32 + g * 4);
        ushort4 m3 = *(const ushort4*)(mb + s3 * 32 + g * 4);
        a0 += lrelu(c0 * b2f(m0.x) + h0) + lrelu(c0 * b2f(m1.x) + h0)
            + lrelu(c0 * b2f(m2.x) + h0) + lrelu(c0 * b2f(m3.x) + h0);
        a1 += lrelu(c1 * b2f(m0.y) + h1) + lrelu(c1 * b2f(m1.y) + h1)
            + lrelu(c1 * b2f(m2.y) + h1) + lrelu(c1 * b2f(m3.y) + h1);
        a2 += lrelu(c2 * b2f(m0.z) + h2) + lrelu(c2 * b2f(m1.z) + h2)
            + lrelu(c2 * b2f(m2.z) + h2) + lrelu(c2 * b2f(m3.z) + h2);
        a3 += lrelu(c3 * b2f(m0.w) + h3) + lrelu(c3 * b2f(m1.w) + h3)
            + lrelu(c3 * b2f(m2.w) + h3) + lrelu(c3 * b2f(m3.w) + h3);
    }
    for (; e < e1; ++e) {
        int s0 = g_csr[e];
        ushort4 m0 = *(const ushort4*)(mb + s0 * 32 + g * 4);
        a0 += lrelu(c0 * b2f(m0.x) + h0);
        a1 += lrelu(c1 * b2f(m0.y) + h1);
        a2 += lrelu(c2 * b2f(m0.z) + h2);
        a3 += lrelu(c3 * b2f(m0.w) + h3);
    }
    *(float4*)(gA + OFF_AGG + n * 32 + g * 4) = make_float4(a0, a1, a2, a3);
}

// ---------------- update linear: PB = [h, agg] @ Wu + bu, stats ----------------
__global__ void k_upd_v17(int off_h, int off_out,
                          const float* __restrict__ Wu_i, const float* __restrict__ bu_i,
                          int st_out)
{
    int j = threadIdx.x & 31, ns = threadIdx.x >> 5;
    float wc[64];
    #pragma unroll
    for (int k = 0; k < 64; ++k) wc[k] = Wu_i[k * 32 + j];
    float bb = bu_i[j];
    __shared__ float sH[8][32];
    __shared__ float sA[8][32];
    __shared__ float red[64];
    if (threadIdx.x < 64) red[threadIdx.x] = 0.f;
    __syncthreads();
    float s1 = 0.f, s2 = 0.f;
    for (int t = blockIdx.x; t < NN / 8; t += gridDim.x) {
        int n = t * 8 + ns;
        sH[ns][j] = gA[off_h + n * 32 + j];
        sA[ns][j] = gA[OFF_AGG + n * 32 + j];
        __syncthreads();
        float acc = bb;
        #pragma unroll
        for (int k = 0; k < 32; k += 4) {
            float4 h4 = *(const float4*)&sH[ns][k];
            acc += h4.x * wc[k] + h4.y * wc[k + 1] + h4.z * wc[k + 2] + h4.w * wc[k + 3];
            float4 a4 = *(const float4*)&sA[ns][k];
            acc += a4.x * wc[32 + k] + a4.y * wc[32 + k + 1] + a4.z * wc[32 + k + 2] + a4.w * wc[32 + k + 3];
        }
        gA[off_out + n * 32 + j] = acc;
        s1 += acc; s2 += acc * acc;
        __syncthreads();
    }
    atomicAdd(&red[j], s1);
    atomicAdd(&red[j + 32], s2);
    __syncthreads();
    if (threadIdx.x < 64)
        atomicAdd(&gA[st_out + (blockIdx.x & (STC - 1)) * 64 + threadIdx.x], red[threadIdx.x]);
}

// ================= MFMA final MLP =================
// All layers computed as Z^T = W_tile * H^T with mfma_f32_16x16x32_bf16.
// D frag: col = lane&15 = node, row = 4*(lane>>4)+reg = out-feature (HW-verified).
// => a lane's 4 acc regs per out-tile are exactly the k-elems of the next layer's
//    B frag (same lane&15 = node, same g = lane>>4). Activations never leave VGPRs.
// Weight frags are pre-packed (k_wprep_v18) in the SAME (g,j)->k order, so the
// contraction is consistent regardless of the HW's internal k permutation.
// Numerics: activations split-bf16 (hi+lo, 2 MFMA terms); weights single bf16;
// output 32->1 layer pure fp32.

typedef __attribute__((ext_vector_type(8))) short bf16x8;
typedef __attribute__((ext_vector_type(4))) float f32x4;

union FC { uint4 u; bf16x8 b; };

#define MFMA(a, b, c) __builtin_amdgcn_mfma_f32_16x16x32_bf16(a, b, c, 0, 0, 0)

__device__ __forceinline__ bf16x8 ld_wf(const uint4* p) {
    FC c; c.u = *p; return c.b;
}

__device__ __forceinline__ f32x4 ld_bias4(const float* p) {
    float4 t = *(const float4*)p;
    f32x4 r; r[0] = t.x; r[1] = t.y; r[2] = t.z; r[3] = t.w; return r;
}

__device__ __forceinline__ f32x4 lrelu4(f32x4 v) {
    f32x4 r;
    #pragma unroll
    for (int k = 0; k < 4; ++k) r[k] = v[k] > 0.f ? v[k] : v[k] * NEG;
    return r;
}

__device__ __forceinline__ void splitpack(const float* v, bf16x8& hi, bf16x8& lo) {
    unsigned int h[4], l[4];
    #pragma unroll
    for (int k = 0; k < 4; ++k) {
        unsigned short h0 = f2b(v[2*k]), h1 = f2b(v[2*k+1]);
        float r0 = v[2*k]   - b2f(h0);
        float r1 = v[2*k+1] - b2f(h1);
        h[k] = (unsigned int)h0 | ((unsigned int)h1 << 16);
        l[k] = (unsigned int)f2b(r0) | ((unsigned int)f2b(r1) << 16);
    }
    FC ch; ch.u = make_uint4(h[0], h[1], h[2], h[3]); hi = ch.b;
    FC cl; cl.u = make_uint4(l[0], l[1], l[2], l[3]); lo = cl.b;
}

// pack weight frags: for lane, elem j: infeat = 32*s + 16*(j>>2) + 4*(lane>>4) + (j&3),
// outfeat = 16*T + (lane&15).  Section layout (shorts): [frag][lane][j], frag = T*nk+s.
__global__ __launch_bounds__(256) void k_wprep_v18(const float* __restrict__ W0,
                                                   const float* __restrict__ W1,
                                                   const float* __restrict__ W2,
                                                   const float* __restrict__ W3)
{
    int i = blockIdx.x * 256 + threadIdx.x;
    if (i >= 51200) return;
    const float* src; int Nout, nk; int r = i;
    if (r < 8192)       { src = W0; Nout = 256; nk = 1; }
    else if (r < 40960) { src = W1; Nout = 128; nk = 8; r -= 8192; }
    else if (r < 49152) { src = W2; Nout = 64;  nk = 4; r -= 40960; }
    else                { src = W3; Nout = 32;  nk = 2; r -= 49152; }
    int frag = r >> 9;
    int lane = (r >> 3) & 63;
    int j = r & 7;
    int T = frag / nk, s = frag - T * nk;
    int g = lane >> 4;
    int outf = T * 16 + (lane & 15);
    int inf = 32 * s + 16 * (j >> 2) + 4 * g + (j & 3);
    unsigned short* dst = (unsigned short*)(gA + OFF_WF);
    dst[i] = f2b(src[inf * Nout + outf]);
}

__global__ __launch_bounds__(256) void k_final_v18(
    int off_h,
    const float* __restrict__ bf0, const float* __restrict__ bf1,
    const float* __restrict__ bf2, const float* __restrict__ bf3,
    const float* __restrict__ Wo,  const float* __restrict__ bo,
    float* __restrict__ out)
{
    int lane = threadIdx.x & 63;
    int wave = threadIdx.x >> 6;
    int c = lane & 15;          // node within 16-tile (B col == D col)
    int g = lane >> 4;          // k/row group
    int nb = blockIdx.x * 128 + wave * 32;
    int n0 = nb + c;
    int n1 = nb + 16 + c;
    int ld0 = min(n0, NN - 1), ld1 = min(n1, NN - 1);

    const float* h = gA + off_h;
    const uint4* WF = (const uint4*)(gA + OFF_WF);

    // ---- input fragments (K=32, one k-step) ----
    float4 ia0 = *(const float4*)&h[ld0 * 32 + 4 * g];
    float4 ib0 = *(const float4*)&h[ld0 * 32 + 16 + 4 * g];
    float4 ia1 = *(const float4*)&h[ld1 * 32 + 4 * g];
    float4 ib1 = *(const float4*)&h[ld1 * 32 + 16 + 4 * g];
    bf16x8 Bh0, Bl0, Bh1, Bl1;
    {
        float v0[8] = {ia0.x, ia0.y, ia0.z, ia0.w, ib0.x, ib0.y, ib0.z, ib0.w};
        float v1[8] = {ia1.x, ia1.y, ia1.z, ia1.w, ib1.x, ib1.y, ib1.z, ib1.w};
        splitpack(v0, Bh0, Bl0);
        splitpack(v1, Bh1, Bl1);
    }

    // ---- L0: 32 -> 256 (16 out-tiles, 1 k-step) ----
    f32x4 A0[16][2];
    #pragma unroll
    for (int t = 0; t < 16; ++t) {
        f32x4 ci = ld_bias4(bf0 + t * 16 + 4 * g);
        bf16x8 w = ld_wf(WF + W0B + t * 64 + lane);
        f32x4 d0 = MFMA(w, Bh0, ci);
        d0 = MFMA(w, Bl0, d0);
        f32x4 d1 = MFMA(w, Bh1, ci);
        d1 = MFMA(w, Bl1, d1);
        A0[t][0] = lrelu4(d0);
        A0[t][1] = lrelu4(d1);
    }

    // ---- L1: 256 -> 128 (8 out-tiles, 8 k-steps) ----
    f32x4 A1[8][2];
    #pragma unroll
    for (int T = 0; T < 8; ++T) {
        f32x4 ci = ld_bias4(bf1 + T * 16 + 4 * g);
        A1[T][0] = ci; A1[T][1] = ci;
    }
    #pragma unroll
    for (int s = 0; s < 8; ++s) {
        bf16x8 bh[2], bl[2];
        #pragma unroll
        for (int u = 0; u < 2; ++u) {
            float vv[8] = {A0[2*s][u][0], A0[2*s][u][1], A0[2*s][u][2], A0[2*s][u][3],
                           A0[2*s+1][u][0], A0[2*s+1][u][1], A0[2*s+1][u][2], A0[2*s+1][u][3]};
            splitpack(vv, bh[u], bl[u]);
        }
        #pragma unroll
        for (int T = 0; T < 8; ++T) {
            bf16x8 w = ld_wf(WF + W1B + (T * 8 + s) * 64 + lane);
            A1[T][0] = MFMA(w, bh[0], A1[T][0]);
            A1[T][0] = MFMA(w, bl[0], A1[T][0]);
            A1[T][1] = MFMA(w, bh[1], A1[T][1]);
            A1[T][1] = MFMA(w, bl[1], A1[T][1]);
        }
    }
    #pragma unroll
    for (int T = 0; T < 8; ++T) { A1[T][0] = lrelu4(A1[T][0]); A1[T][1] = lrelu4(A1[T][1]); }

    // ---- L2: 128 -> 64 (4 out-tiles, 4 k-steps) ----
    f32x4 A2[4][2];
    #pragma unroll
    for (int T = 0; T < 4; ++T) {
        f32x4 ci = ld_bias4(bf2 + T * 16 + 4 * g);
        A2[T][0] = ci; A2[T][1] = ci;
    }
    #pragma unroll
    for (int s = 0; s < 4; ++s) {
        bf16x8 bh[2], bl[2];
        #pragma unroll
        for (int u = 0; u < 2; ++u) {
            float vv[8] = {A1[2*s][u][0], A1[2*s][u][1], A1[2*s][u][2], A1[2*s][u][3],
                           A1[2*s+1][u][0], A1[2*s+1][u][1], A1[2*s+1][u][2], A1[2*s+1][u][3]};
            splitpack(vv, bh[u], bl[u]);
        }
        #pragma unroll
        for (int T = 0; T < 4; ++T) {
            bf16x8 w = ld_wf(WF + W2B + (T * 4 + s) * 64 + lane);
            A2[T][0] = MFMA(w, bh[0], A2[T][0]);
            A2[T][0] = MFMA(w, bl[0], A2[T][0]);
            A2[T][1] = MFMA(w, bh[1], A2[T][1]);
            A2[T][1] = MFMA(w, bl[1], A2[T][1]);
        }
    }
    #pragma unroll
    for (int T = 0; T < 4; ++T) { A2[T][0] = lrelu4(A2[T][0]); A2[T][1] = lrelu4(A2[T][1]); }

    // ---- L3: 64 -> 32 (2 out-tiles, 2 k-steps) ----
    f32x4 A3[2][2];
    #pragma unroll
    for (int T = 0; T < 2; ++T) {
        f32x4 ci = ld_bias4(bf3 + T * 16 + 4 * g);
        A3[T][0] = ci; A3[T][1] = ci;
    }
    #pragma unroll
    for (int s = 0; s < 2; ++s) {
        bf16x8 bh[2], bl[2];
        #pragma unroll
        for (int u = 0; u < 2; ++u) {
            float vv[8] = {A2[2*s][u][0], A2[2*s][u][1], A2[2*s][u][2], A2[2*s][u][3],
                           A2[2*s+1][u][0], A2[2*s+1][u][1], A2[2*s+1][u][2], A2[2*s+1][u][3]};
            splitpack(vv, bh[u], bl[u]);
        }
        #pragma unroll
        for (int T = 0; T < 2; ++T) {
            bf16x8 w = ld_wf(WF + W3B + (T * 2 + s) * 64 + lane);
            A3[T][0] = MFMA(w, bh[0], A3[T][0]);
            A3[T][0] = MFMA(w, bl[0], A3[T][0]);
            A3[T][1] = MFMA(w, bh[1], A3[T][1]);
            A3[T][1] = MFMA(w, bl[1], A3[T][1]);
        }
    }
    #pragma unroll
    for (int T = 0; T < 2; ++T) { A3[T][0] = lrelu4(A3[T][0]); A3[T][1] = lrelu4(A3[T][1]); }

    // ---- Out: 32 -> 1 + sigmoid (fp32, shuffle-reduce over g groups) ----
    float4 woa = *(const float4*)&Wo[4 * g];
    float4 wob = *(const float4*)&Wo[16 + 4 * g];
    float z0 = A3[0][0][0]*woa.x + A3[0][0][1]*woa.y + A3[0][0][2]*woa.z + A3[0][0][3]*woa.w
             + A3[1][0][0]*wob.x + A3[1][0][1]*wob.y + A3[1][0][2]*wob.z + A3[1][0][3]*wob.w;
    float z1 = A3[0][1][0]*woa.x + A3[0][1][1]*woa.y + A3[0][1][2]*woa.z + A3[0][1][3]*woa.w
             + A3[1][1][0]*wob.x + A3[1][1][1]*wob.y + A3[1][1][2]*wob.z + A3[1][1][3]*wob.w;
    z0 += __shfl_xor(z0, 16); z0 += __shfl_xor(z0, 32);
    z1 += __shfl_xor(z1, 16); z1 += __shfl_xor(z1, 32);
    float bb = bo[0];
    if (g == 0 && n0 < NN) out[n0] = 1.f / (1.f + __expf(-(z0 + bb)));
    if (g == 1 && n1 < NN) out[n1] = 1.f / (1.f + __expf(-(z1 + bb)));
}

extern "C" void kernel_launch(void* const* d_in, const int* in_sizes, int n_in,
                              void* d_out, int out_size, void* d_ws, size_t ws_size,
                              hipStream_t stream)
{
    (void)in_sizes; (void)n_in; (void)out_size; (void)d_ws; (void)ws_size;
    float* out = (float*)d_out;

    const float* x   = (const float*)d_in[0];
    const int*  col  = (const int*) d_in[1];
    const float* Wi0 = (const float*)d_in[2];
    const float* bi0 = (const float*)d_in[3];
    const float* gi0 = (const float*)d_in[4];
    const float* bei0= (const float*)d_in[5];
    const float* Wi1 = (const float*)d_in[6];
    const float* bi1 = (const float*)d_in[7];
    const float* gi1 = (const float*)d_in[8];
    const float* bei1= (const float*)d_in[9];
    const float* Wm  = (const float*)d_in[10];
    const float* bm  = (const float*)d_in[11];
    const float* gm  = (const float*)d_in[12];
    const float* bem = (const float*)d_in[13];
    const float* Wu  = (const float*)d_in[14];
    const float* bu  = (const float*)d_in[15];
    const float* gu  = (const float*)d_in[16];
    const float* beu = (const float*)d_in[17];
    const float* Wf0 = (const float*)d_in[18];
    const float* bf0 = (const float*)d_in[19];
    const float* Wf1 = (const float*)d_in[20];
    const float* bf1 = (const float*)d_in[21];
    const float* Wf2 = (const float*)d_in[22];
    const float* bf2 = (const float*)d_in[23];
    const float* Wf3 = (const float*)d_in[24];
    const float* bf3 = (const float*)d_in[25];
    const float* Wo  = (const float*)d_in[26];
    const float* bo  = (const float*)d_in[27];

    const int st_i0 = OFF_STATS;
    const int st_i1 = OFF_STATS + ST_STRIDE;
    const int st_m  = OFF_STATS + 2 * ST_STRIDE;    // + i*ST_STRIDE
    const int st_u  = OFF_STATS + 12 * ST_STRIDE;   // + i*ST_STRIDE

    const int RING[4] = { OFF_RING, OFF_RING + NV, OFF_RING + 2 * NV, OFF_RING + 3 * NV };

    dim3 blk(256);
    k_zero_v17<<<NBLK, blk, 0, stream>>>();
    k_count_v17<<<6250, blk, 0, stream>>>(col);
    k_bsum_v17<<<NBLK, blk, 0, stream>>>();
    k_bscan_v17<<<1, 512, 0, stream>>>();
    k_bexp_v17<<<NBLK, blk, 0, stream>>>();
    k_fill_v17<<<6250, blk, 0, stream>>>(col);
    k_wprep_v18<<<200, blk, 0, stream>>>(Wf0, Wf1, Wf2, Wf3);

    // init MLP: x -> h0 (ring[0]); last k_nl chains layer-0 msg linear into bf16 MSGB
    k_init0_v17<<<1024, blk, 0, stream>>>(x, Wi0, bi0);
    k_nl_v17<<<1024, blk, 0, stream>>>(OFF_PA, OFF_PB, 0, st_i0, gi0, bei0, -1, -1, Wi1, bi1, st_i1);
    k_nl_v17<<<1024, blk, 0, stream>>>(OFF_PB, 0, 1, st_i1, gi1, bei1, -1, RING[0], Wm, bm, st_m);

    for (int i = 0; i < 10; ++i) {
        int h_cur = RING[i & 3];
        int h_new = RING[(i + 1) & 3];
        int resid = (i >= 2) ? RING[(i - 2) & 3] : -1;
        k_gather_v17<<<3125, blk, 0, stream>>>(st_m + i * ST_STRIDE, gm + i * 32, bem + i * 32);
        k_upd_v17<<<1024, blk, 0, stream>>>(h_cur, OFF_PB, Wu + i * 2048, bu + i * 32,
                                            st_u + i * ST_STRIDE);
        const float* Wn = (i < 9) ? (Wm + (i + 1) * 1024) : nullptr;
        const float* bn = (i < 9) ? (bm + (i + 1) * 32) : nullptr;
        int st_next = (i < 9) ? (st_m + (i + 1) * ST_STRIDE) : 0;
        k_nl_v17<<<1024, blk, 0, stream>>>(OFF_PB, 0, 1, st_u + i * ST_STRIDE,
                                           gu + i * 32, beu + i * 32,
                                           resid, h_new, Wn, bn, st_next);
    }

    k_final_v18<<<782, blk, 0, stream>>>(RING[2], bf0, bf1, bf2, bf3, Wo, bo, out);
}

// Round 3
// 978.257 us; speedup vs baseline: 1.3250x; 1.1635x over previous
//
#include <hip/hip_runtime.h>
#include <hip/hip_bf16.h>

#define NN 100000
#define NEDGE 1600000
#define NV (NN*32)
#define NEG 0.01f
#define EPS 1e-5f
#define NBLK 391            // ceil(NN/256)
#define NBKT 391            // ceil(NN/256) node buckets (256 nodes each)
#define CHUNK 4096          // edges per binning block
#define NCBLK 391           // ceil(NEDGE/CHUNK)
#define DCAP 6144           // LDS stage capacity in k_csr (mean 4092 + 32 sigma)
#define STC 64              // stat copies (contention spread)
#define ST_STRIDE 4096      // STC * 64

// ---- static device arena (fp32) ----
#define OFF_STATS 0
#define STATS_F  (22*ST_STRIDE)
#define OFF_PA   STATS_F
#define OFF_PB   (OFF_PA + NV)
#define OFF_AGG  (OFF_PB + NV)
#define OFF_MSGB (OFF_AGG + NV)          // NV bf16 = NV/2 floats
#define OFF_RING (OFF_MSGB + NV/2)
#define OFF_WF   (OFF_RING + 4*NV)       // bf16 weight frags for final MLP (51200 shorts)
#define ARENA_F  (OFF_WF + 25600)

// weight-frag section bases in uint4 (16B) units
#define W0B 0
#define W1B 1024
#define W2B 5120
#define W3B 6144

__device__ __align__(16) float gA[ARENA_F];
__device__ int g_rowptr[NN + 1];
__device__ int g_csr[NEDGE];
__device__ int g_bin[NEDGE];       // bucket-grouped packed edges: (src<<8)|dlocal
__device__ int g_bcnt[NBKT];
__device__ int g_boff[NBKT];
__device__ int g_btail[NBKT];

__device__ __forceinline__ float lrelu(float v) { return v > 0.f ? v : v * NEG; }
__device__ __forceinline__ unsigned short f2b(float v) {
    __hip_bfloat16 b = __float2bfloat16(v);
    return *reinterpret_cast<unsigned short*>(&b);
}
__device__ __forceinline__ float b2f(unsigned short u) {
    __hip_bfloat16 b = *reinterpret_cast<__hip_bfloat16*>(&u);
    return __bfloat162float(b);
}

// ---------------- zero stats + bucket counts ----------------
__global__ void k_zero_v19()
{
    int i = blockIdx.x * 256 + threadIdx.x;
    if (i < STATS_F) gA[i] = 0.f;
    if (i < NBKT) g_bcnt[i] = 0;
}

// ---------------- bucket histogram (LDS-staged, low-contention) ----------------
__global__ __launch_bounds__(256) void k_bcnt_v19(const int* __restrict__ col)
{
    __shared__ int hist[NBKT];
    int tid = threadIdx.x;
    for (int b = tid; b < NBKT; b += 256) hist[b] = 0;
    __syncthreads();
    int e0 = blockIdx.x * CHUNK;
    #pragma unroll
    for (int r = 0; r < CHUNK / 256; ++r) {
        int e = e0 + r * 256 + tid;
        if (e < NEDGE) atomicAdd(&hist[col[NEDGE + e] >> 8], 1);
    }
    __syncthreads();
    for (int b = tid; b < NBKT; b += 256) {
        int v = hist[b];
        if (v) atomicAdd(&g_bcnt[b], v);
    }
}

// ---------------- scan bucket counts -> offsets + tails ----------------
__global__ __launch_bounds__(512) void k_bscan_v19()
{
    __shared__ int s[512];
    int t = threadIdx.x;
    int v = (t < NBKT) ? g_bcnt[t] : 0;
    s[t] = v;
    __syncthreads();
    for (int off = 1; off < 512; off <<= 1) {
        int u = (t >= off) ? s[t - off] : 0;
        __syncthreads();
        s[t] += u;
        __syncthreads();
    }
    if (t < NBKT) {
        int o = s[t] - v;
        g_boff[t] = o;
        g_btail[t] = o;
    }
}

// ---------------- bin edges into bucket-contiguous regions (chunked append) ----------------
__global__ __launch_bounds__(256) void k_binfill_v19(const int* __restrict__ col)
{
    __shared__ int ssrc[CHUNK];
    __shared__ int sdst[CHUNK];
    __shared__ int hist[NBKT];
    __shared__ int boffL[NBKT];
    __shared__ int cnt2[NBKT];
    int tid = threadIdx.x;
    for (int b = tid; b < NBKT; b += 256) { hist[b] = 0; cnt2[b] = 0; }
    __syncthreads();
    int e0 = blockIdx.x * CHUNK;
    #pragma unroll
    for (int r = 0; r < CHUNK / 256; ++r) {
        int i = r * 256 + tid;
        int e = e0 + i;
        if (e < NEDGE) {
            int s = col[e];
            int d = col[NEDGE + e];
            ssrc[i] = s;
            sdst[i] = d;
            atomicAdd(&hist[d >> 8], 1);
        }
    }
    __syncthreads();
    for (int b = tid; b < NBKT; b += 256) {
        int h = hist[b];
        if (h) boffL[b] = atomicAdd(&g_btail[b], h);
    }
    __syncthreads();
    #pragma unroll
    for (int r = 0; r < CHUNK / 256; ++r) {
        int i = r * 256 + tid;
        int e = e0 + i;
        if (e < NEDGE) {
            int d = sdst[i];
            int b = d >> 8;
            int rk = atomicAdd(&cnt2[b], 1);
            g_bin[boffL[b] + rk] = (ssrc[i] << 8) | (d & 255);
        }
    }
}

// ---------------- per-bucket local sort -> exact CSR (coalesced block-local writes) ----------------
__global__ __launch_bounds__(256) void k_csr_v19()
{
    __shared__ int stg[DCAP];
    __shared__ int c1[256];
    __shared__ int sc[256];
    __shared__ int sl[256];
    __shared__ int c2[256];
    int tid = threadIdx.x, b = blockIdx.x;
    int base = g_boff[b];
    int cntE = g_bcnt[b];
    c1[tid] = 0; c2[tid] = 0;
    __syncthreads();
    for (int i = tid; i < cntE; i += 256) {
        int p = g_bin[base + i];
        if (i < DCAP) stg[i] = p;
        atomicAdd(&c1[p & 255], 1);
    }
    __syncthreads();
    // inclusive scan of per-node counts
    int v = c1[tid];
    sc[tid] = v;
    __syncthreads();
    for (int off = 1; off < 256; off <<= 1) {
        int u = (tid >= off) ? sc[tid - off] : 0;
        __syncthreads();
        sc[tid] += u;
        __syncthreads();
    }
    int loff = sc[tid] - v;
    sl[tid] = loff;
    int node = b * 256 + tid;
    if (node < NN) g_rowptr[node] = base + loff;
    if (b == NBKT - 1 && tid == 0) g_rowptr[NN] = NEDGE;
    __syncthreads();
    for (int i = tid; i < cntE; i += 256) {
        int p = (i < DCAP) ? stg[i] : g_bin[base + i];
        int dl = p & 255;
        int rk = atomicAdd(&c2[dl], 1);
        g_csr[base + sl[dl] + rk] = p >> 8;
    }
}

// ---------------- init layer 0: PA = x*Wi0 + bi0, stats ----------------
__global__ void k_init0_v17(const float* __restrict__ x, const float* __restrict__ Wi0,
                            const float* __restrict__ bi0)
{
    int j = threadIdx.x & 31, ns = threadIdx.x >> 5;
    float w = Wi0[j];
    float bb = bi0[j];
    __shared__ float red[64];
    if (threadIdx.x < 64) red[threadIdx.x] = 0.f;
    __syncthreads();
    float s1 = 0.f, s2 = 0.f;
    for (int t = blockIdx.x; t < NN / 8; t += gridDim.x) {
        int n = t * 8 + ns;
        float v = x[n] * w + bb;
        gA[OFF_PA + n * 32 + j] = v;
        s1 += v; s2 += v * v;
    }
    atomicAdd(&red[j], s1);
    atomicAdd(&red[j + 32], s2);
    __syncthreads();
    if (threadIdx.x < 64)
        atomicAdd(&gA[OFF_STATS + (blockIdx.x & (STC - 1)) * 64 + threadIdx.x], red[threadIdx.x]);
}

// ------- BN+LReLU (+resid) (+feats store) (+fused next 32x32 linear + stats) -------
__global__ void k_nl_v17(int off_in, int off_out, int out_msg, int st_in,
                         const float* __restrict__ gamma, const float* __restrict__ beta,
                         int off_resid, int off_feats,
                         const float* __restrict__ Wn, const float* __restrict__ bn,
                         int st_out)
{
    int j = threadIdx.x & 31, ns = threadIdx.x >> 5;
    __shared__ float sstat[64];
    __shared__ float red[64];
    if (threadIdx.x < 64) {
        red[threadIdx.x] = 0.f;
        float acc = 0.f;
        int base = st_in + threadIdx.x;
        #pragma unroll 8
        for (int c = 0; c < STC; ++c) acc += gA[base + c * 64];
        sstat[threadIdx.x] = acc;
    }
    __syncthreads();
    float mean = sstat[j] * (1.f / NN);
    float var  = sstat[32 + j] * (1.f / NN) - mean * mean;
    float scale = gamma[j] * rsqrtf(var + EPS);
    float shift = beta[j] - mean * scale;

    float wc[32]; float bb = 0.f;
    if (Wn) {
        #pragma unroll
        for (int k = 0; k < 32; ++k) wc[k] = Wn[k * 32 + j];
        bb = bn[j];
    }
    unsigned short* mb = (unsigned short*)(gA + OFF_MSGB);
    __shared__ float sH[8][32];
    float s1 = 0.f, s2 = 0.f;
    for (int t = blockIdx.x; t < NN / 8; t += gridDim.x) {
        int n = t * 8 + ns;
        float v = gA[off_in + n * 32 + j];
        v = lrelu(scale * v + shift);
        if (off_resid >= 0) v += gA[off_resid + n * 32 + j];
        if (off_feats >= 0) gA[off_feats + n * 32 + j] = v;
        if (Wn) {
            sH[ns][j] = v;
            __syncthreads();
            float acc = bb;
            #pragma unroll
            for (int k = 0; k < 32; k += 4) {
                float4 h4 = *(const float4*)&sH[ns][k];
                acc += h4.x * wc[k] + h4.y * wc[k + 1] + h4.z * wc[k + 2] + h4.w * wc[k + 3];
            }
            if (out_msg) mb[n * 32 + j] = f2b(acc);
            else gA[off_out + n * 32 + j] = acc;
            s1 += acc; s2 += acc * acc;
            __syncthreads();
        }
    }
    if (Wn) {
        atomicAdd(&red[j], s1);
        atomicAdd(&red[j + 32], s2);
        __syncthreads();
        if (threadIdx.x < 64)
            atomicAdd(&gA[st_out + (blockIdx.x & (STC - 1)) * 64 + threadIdx.x], red[threadIdx.x]);
    }
}

// ---------------- CSR gather with fused msg BN+LReLU (bf16 pre-acts), 4-edge unroll ----------------
__global__ __launch_bounds__(256) void k_gather_v17(int st,
                                                    const float* __restrict__ gm,
                                                    const float* __restrict__ bem)
{
    __shared__ float sstat[64];
    __shared__ float sc[32], sh[32];
    int tid = threadIdx.x;
    if (tid < 64) {
        float acc = 0.f;
        int base = st + tid;
        #pragma unroll 8
        for (int c = 0; c < STC; ++c) acc += gA[base + c * 64];
        sstat[tid] = acc;
    }
    __syncthreads();
    if (tid < 32) {
        float mean = sstat[tid] * (1.f / NN);
        float var  = sstat[32 + tid] * (1.f / NN) - mean * mean;
        float s = gm[tid] * rsqrtf(var + EPS);
        sc[tid] = s;
        sh[tid] = bem[tid] - mean * s;
    }
    __syncthreads();
    int n = blockIdx.x * 32 + (tid >> 3);
    int g = tid & 7;
    int e0 = g_rowptr[n], e1 = g_rowptr[n + 1];
    const unsigned short* mb = (const unsigned short*)(gA + OFF_MSGB);
    float c0 = sc[g*4], c1 = sc[g*4+1], c2 = sc[g*4+2], c3 = sc[g*4+3];
    float h0 = sh[g*4], h1 = sh[g*4+1], h2 = sh[g*4+2], h3 = sh[g*4+3];
    float a0 = 0.f, a1 = 0.f, a2 = 0.f, a3 = 0.f;
    int e = e0;
    for (; e + 3 < e1; e += 4) {
        int s0 = g_csr[e];
        int s1 = g_csr[e + 1];
        int s2 = g_csr[e + 2];
        int s3 = g_csr[e + 3];
        ushort4 m0 = *(const ushort4*)(mb + s0 * 32 + g * 4);
        ushort4 m1 = *(const ushort4*)(mb + s1 * 32 + g * 4);
        ushort4 m2 = *(const ushort4*)(mb + s2 * 32 + g * 4);
        ushort4 m3 = *(const ushort4*)(mb + s3 * 32 + g * 4);
        a0 += lrelu(c0 * b2f(m0.x) + h0) + lrelu(c0 * b2f(m1.x) + h0)
            + lrelu(c0 * b2f(m2.x) + h0) + lrelu(c0 * b2f(m3.x) + h0);
        a1 += lrelu(c1 * b2f(m0.y) + h1) + lrelu(c1 * b2f(m1.y) + h1)
            + lrelu(c1 * b2f(m2.y) + h1) + lrelu(c1 * b2f(m3.y) + h1);
        a2 += lrelu(c2 * b2f(m0.z) + h2) + lrelu(c2 * b2f(m1.z) + h2)
            + lrelu(c2 * b2f(m2.z) + h2) + lrelu(c2 * b2f(m3.z) + h2);
        a3 += lrelu(c3 * b2f(m0.w) + h3) + lrelu(c3 * b2f(m1.w) + h3)
            + lrelu(c3 * b2f(m2.w) + h3) + lrelu(c3 * b2f(m3.w) + h3);
    }
    for (; e < e1; ++e) {
        int s0 = g_csr[e];
        ushort4 m0 = *(const ushort4*)(mb + s0 * 32 + g * 4);
        a0 += lrelu(c0 * b2f(m0.x) + h0);
        a1 += lrelu(c1 * b2f(m0.y) + h1);
        a2 += lrelu(c2 * b2f(m0.z) + h2);
        a3 += lrelu(c3 * b2f(m0.w) + h3);
    }
    *(float4*)(gA + OFF_AGG + n * 32 + g * 4) = make_float4(a0, a1, a2, a3);
}

// ---------------- update linear: PB = [h, agg] @ Wu + bu, stats ----------------
__global__ void k_upd_v17(int off_h, int off_out,
                          const float* __restrict__ Wu_i, const float* __restrict__ bu_i,
                          int st_out)
{
    int j = threadIdx.x & 31, ns = threadIdx.x >> 5;
    float wc[64];
    #pragma unroll
    for (int k = 0; k < 64; ++k) wc[k] = Wu_i[k * 32 + j];
    float bb = bu_i[j];
    __shared__ float sH[8][32];
    __shared__ float sA[8][32];
    __shared__ float red[64];
    if (threadIdx.x < 64) red[threadIdx.x] = 0.f;
    __syncthreads();
    float s1 = 0.f, s2 = 0.f;
    for (int t = blockIdx.x; t < NN / 8; t += gridDim.x) {
        int n = t * 8 + ns;
        sH[ns][j] = gA[off_h + n * 32 + j];
        sA[ns][j] = gA[OFF_AGG + n * 32 + j];
        __syncthreads();
        float acc = bb;
        #pragma unroll
        for (int k = 0; k < 32; k += 4) {
            float4 h4 = *(const float4*)&sH[ns][k];
            acc += h4.x * wc[k] + h4.y * wc[k + 1] + h4.z * wc[k + 2] + h4.w * wc[k + 3];
            float4 a4 = *(const float4*)&sA[ns][k];
            acc += a4.x * wc[32 + k] + a4.y * wc[32 + k + 1] + a4.z * wc[32 + k + 2] + a4.w * wc[32 + k + 3];
        }
        gA[off_out + n * 32 + j] = acc;
        s1 += acc; s2 += acc * acc;
        __syncthreads();
    }
    atomicAdd(&red[j], s1);
    atomicAdd(&red[j + 32], s2);
    __syncthreads();
    if (threadIdx.x < 64)
        atomicAdd(&gA[st_out + (blockIdx.x & (STC - 1)) * 64 + threadIdx.x], red[threadIdx.x]);
}

// ================= MFMA final MLP =================
// All layers computed as Z^T = W_tile * H^T with mfma_f32_16x16x32_bf16.
// D frag: col = lane&15 = node, row = 4*(lane>>4)+reg = out-feature (HW-verified).
// => a lane's 4 acc regs per out-tile are exactly the k-elems of the next layer's
//    B frag (same lane&15 = node, same g = lane>>4). Activations never leave VGPRs.
// Weight frags are pre-packed (k_wprep_v18) in the SAME (g,j)->k order, so the
// contraction is consistent regardless of the HW's internal k permutation.
// Numerics: activations split-bf16 (hi+lo, 2 MFMA terms); weights single bf16;
// output 32->1 layer pure fp32.

typedef __attribute__((ext_vector_type(8))) short bf16x8;
typedef __attribute__((ext_vector_type(4))) float f32x4;

union FC { uint4 u; bf16x8 b; };

#define MFMA(a, b, c) __builtin_amdgcn_mfma_f32_16x16x32_bf16(a, b, c, 0, 0, 0)

__device__ __forceinline__ bf16x8 ld_wf(const uint4* p) {
    FC c; c.u = *p; return c.b;
}

__device__ __forceinline__ f32x4 ld_bias4(const float* p) {
    float4 t = *(const float4*)p;
    f32x4 r; r[0] = t.x; r[1] = t.y; r[2] = t.z; r[3] = t.w; return r;
}

__device__ __forceinline__ f32x4 lrelu4(f32x4 v) {
    f32x4 r;
    #pragma unroll
    for (int k = 0; k < 4; ++k) r[k] = v[k] > 0.f ? v[k] : v[k] * NEG;
    return r;
}

__device__ __forceinline__ void splitpack(const float* v, bf16x8& hi, bf16x8& lo) {
    unsigned int h[4], l[4];
    #pragma unroll
    for (int k = 0; k < 4; ++k) {
        unsigned short h0 = f2b(v[2*k]), h1 = f2b(v[2*k+1]);
        float r0 = v[2*k]   - b2f(h0);
        float r1 = v[2*k+1] - b2f(h1);
        h[k] = (unsigned int)h0 | ((unsigned int)h1 << 16);
        l[k] = (unsigned int)f2b(r0) | ((unsigned int)f2b(r1) << 16);
    }
    FC ch; ch.u = make_uint4(h[0], h[1], h[2], h[3]); hi = ch.b;
    FC cl; cl.u = make_uint4(l[0], l[1], l[2], l[3]); lo = cl.b;
}

// pack weight frags: for lane, elem j: infeat = 32*s + 16*(j>>2) + 4*(lane>>4) + (j&3),
// outfeat = 16*T + (lane&15).  Section layout (shorts): [frag][lane][j], frag = T*nk+s.
__global__ __launch_bounds__(256) void k_wprep_v18(const float* __restrict__ W0,
                                                   const float* __restrict__ W1,
                                                   const float* __restrict__ W2,
                                                   const float* __restrict__ W3)
{
    int i = blockIdx.x * 256 + threadIdx.x;
    if (i >= 51200) return;
    const float* src; int Nout, nk; int r = i;
    if (r < 8192)       { src = W0; Nout = 256; nk = 1; }
    else if (r < 40960) { src = W1; Nout = 128; nk = 8; r -= 8192; }
    else if (r < 49152) { src = W2; Nout = 64;  nk = 4; r -= 40960; }
    else                { src = W3; Nout = 32;  nk = 2; r -= 49152; }
    int frag = r >> 9;
    int lane = (r >> 3) & 63;
    int j = r & 7;
    int T = frag / nk, s = frag - T * nk;
    int g = lane >> 4;
    int outf = T * 16 + (lane & 15);
    int inf = 32 * s + 16 * (j >> 2) + 4 * g + (j & 3);
    unsigned short* dst = (unsigned short*)(gA + OFF_WF);
    dst[i] = f2b(src[inf * Nout + outf]);
}

__global__ __launch_bounds__(256) void k_final_v18(
    int off_h,
    const float* __restrict__ bf0, const float* __restrict__ bf1,
    const float* __restrict__ bf2, const float* __restrict__ bf3,
    const float* __restrict__ Wo,  const float* __restrict__ bo,
    float* __restrict__ out)
{
    int lane = threadIdx.x & 63;
    int wave = threadIdx.x >> 6;
    int c = lane & 15;          // node within 16-tile (B col == D col)
    int g = lane >> 4;          // k/row group
    int nb = blockIdx.x * 128 + wave * 32;
    int n0 = nb + c;
    int n1 = nb + 16 + c;
    int ld0 = min(n0, NN - 1), ld1 = min(n1, NN - 1);

    const float* h = gA + off_h;
    const uint4* WF = (const uint4*)(gA + OFF_WF);

    // ---- input fragments (K=32, one k-step) ----
    float4 ia0 = *(const float4*)&h[ld0 * 32 + 4 * g];
    float4 ib0 = *(const float4*)&h[ld0 * 32 + 16 + 4 * g];
    float4 ia1 = *(const float4*)&h[ld1 * 32 + 4 * g];
    float4 ib1 = *(const float4*)&h[ld1 * 32 + 16 + 4 * g];
    bf16x8 Bh0, Bl0, Bh1, Bl1;
    {
        float v0[8] = {ia0.x, ia0.y, ia0.z, ia0.w, ib0.x, ib0.y, ib0.z, ib0.w};
        float v1[8] = {ia1.x, ia1.y, ia1.z, ia1.w, ib1.x, ib1.y, ib1.z, ib1.w};
        splitpack(v0, Bh0, Bl0);
        splitpack(v1, Bh1, Bl1);
    }

    // ---- L0: 32 -> 256 (16 out-tiles, 1 k-step) ----
    f32x4 A0[16][2];
    #pragma unroll
    for (int t = 0; t < 16; ++t) {
        f32x4 ci = ld_bias4(bf0 + t * 16 + 4 * g);
        bf16x8 w = ld_wf(WF + W0B + t * 64 + lane);
        f32x4 d0 = MFMA(w, Bh0, ci);
        d0 = MFMA(w, Bl0, d0);
        f32x4 d1 = MFMA(w, Bh1, ci);
        d1 = MFMA(w, Bl1, d1);
        A0[t][0] = lrelu4(d0);
        A0[t][1] = lrelu4(d1);
    }

    // ---- L1: 256 -> 128 (8 out-tiles, 8 k-steps) ----
    f32x4 A1[8][2];
    #pragma unroll
    for (int T = 0; T < 8; ++T) {
        f32x4 ci = ld_bias4(bf1 + T * 16 + 4 * g);
        A1[T][0] = ci; A1[T][1] = ci;
    }
    #pragma unroll
    for (int s = 0; s < 8; ++s) {
        bf16x8 bh[2], bl[2];
        #pragma unroll
        for (int u = 0; u < 2; ++u) {
            float vv[8] = {A0[2*s][u][0], A0[2*s][u][1], A0[2*s][u][2], A0[2*s][u][3],
                           A0[2*s+1][u][0], A0[2*s+1][u][1], A0[2*s+1][u][2], A0[2*s+1][u][3]};
            splitpack(vv, bh[u], bl[u]);
        }
        #pragma unroll
        for (int T = 0; T < 8; ++T) {
            bf16x8 w = ld_wf(WF + W1B + (T * 8 + s) * 64 + lane);
            A1[T][0] = MFMA(w, bh[0], A1[T][0]);
            A1[T][0] = MFMA(w, bl[0], A1[T][0]);
            A1[T][1] = MFMA(w, bh[1], A1[T][1]);
            A1[T][1] = MFMA(w, bl[1], A1[T][1]);
        }
    }
    #pragma unroll
    for (int T = 0; T < 8; ++T) { A1[T][0] = lrelu4(A1[T][0]); A1[T][1] = lrelu4(A1[T][1]); }

    // ---- L2: 128 -> 64 (4 out-tiles, 4 k-steps) ----
    f32x4 A2[4][2];
    #pragma unroll
    for (int T = 0; T < 4; ++T) {
        f32x4 ci = ld_bias4(bf2 + T * 16 + 4 * g);
        A2[T][0] = ci; A2[T][1] = ci;
    }
    #pragma unroll
    for (int s = 0; s < 4; ++s) {
        bf16x8 bh[2], bl[2];
        #pragma unroll
        for (int u = 0; u < 2; ++u) {
            float vv[8] = {A1[2*s][u][0], A1[2*s][u][1], A1[2*s][u][2], A1[2*s][u][3],
                           A1[2*s+1][u][0], A1[2*s+1][u][1], A1[2*s+1][u][2], A1[2*s+1][u][3]};
            splitpack(vv, bh[u], bl[u]);
        }
        #pragma unroll
        for (int T = 0; T < 4; ++T) {
            bf16x8 w = ld_wf(WF + W2B + (T * 4 + s) * 64 + lane);
            A2[T][0] = MFMA(w, bh[0], A2[T][0]);
            A2[T][0] = MFMA(w, bl[0], A2[T][0]);
            A2[T][1] = MFMA(w, bh[1], A2[T][1]);
            A2[T][1] = MFMA(w, bl[1], A2[T][1]);
        }
    }
    #pragma unroll
    for (int T = 0; T < 4; ++T) { A2[T][0] = lrelu4(A2[T][0]); A2[T][1] = lrelu4(A2[T][1]); }

    // ---- L3: 64 -> 32 (2 out-tiles, 2 k-steps) ----
    f32x4 A3[2][2];
    #pragma unroll
    for (int T = 0; T < 2; ++T) {
        f32x4 ci = ld_bias4(bf3 + T * 16 + 4 * g);
        A3[T][0] = ci; A3[T][1] = ci;
    }
    #pragma unroll
    for (int s = 0; s < 2; ++s) {
        bf16x8 bh[2], bl[2];
        #pragma unroll
        for (int u = 0; u < 2; ++u) {
            float vv[8] = {A2[2*s][u][0], A2[2*s][u][1], A2[2*s][u][2], A2[2*s][u][3],
                           A2[2*s+1][u][0], A2[2*s+1][u][1], A2[2*s+1][u][2], A2[2*s+1][u][3]};
            splitpack(vv, bh[u], bl[u]);
        }
        #pragma unroll
        for (int T = 0; T < 2; ++T) {
            bf16x8 w = ld_wf(WF + W3B + (T * 2 + s) * 64 + lane);
            A3[T][0] = MFMA(w, bh[0], A3[T][0]);
            A3[T][0] = MFMA(w, bl[0], A3[T][0]);
            A3[T][1] = MFMA(w, bh[1], A3[T][1]);
            A3[T][1] = MFMA(w, bl[1], A3[T][1]);
        }
    }
    #pragma unroll
    for (int T = 0; T < 2; ++T) { A3[T][0] = lrelu4(A3[T][0]); A3[T][1] = lrelu4(A3[T][1]); }

    // ---- Out: 32 -> 1 + sigmoid (fp32, shuffle-reduce over g groups) ----
    float4 woa = *(const float4*)&Wo[4 * g];
    float4 wob = *(const float4*)&Wo[16 + 4 * g];
    float z0 = A3[0][0][0]*woa.x + A3[0][0][1]*woa.y + A3[0][0][2]*woa.z + A3[0][0][3]*woa.w
             + A3[1][0][0]*wob.x + A3[1][0][1]*wob.y + A3[1][0][2]*wob.z + A3[1][0][3]*wob.w;
    float z1 = A3[0][1][0]*woa.x + A3[0][1][1]*woa.y + A3[0][1][2]*woa.z + A3[0][1][3]*woa.w
             + A3[1][1][0]*wob.x + A3[1][1][1]*wob.y + A3[1][1][2]*wob.z + A3[1][1][3]*wob.w;
    z0 += __shfl_xor(z0, 16); z0 += __shfl_xor(z0, 32);
    z1 += __shfl_xor(z1, 16); z1 += __shfl_xor(z1, 32);
    float bb = bo[0];
    if (g == 0 && n0 < NN) out[n0] = 1.f / (1.f + __expf(-(z0 + bb)));
    if (g == 1 && n1 < NN) out[n1] = 1.f / (1.f + __expf(-(z1 + bb)));
}

extern "C" void kernel_launch(void* const* d_in, const int* in_sizes, int n_in,
                              void* d_out, int out_size, void* d_ws, size_t ws_size,
                              hipStream_t stream)
{
    (void)in_sizes; (void)n_in; (void)out_size; (void)d_ws; (void)ws_size;
    float* out = (float*)d_out;

    const float* x   = (const float*)d_in[0];
    const int*  col  = (const int*) d_in[1];
    const float* Wi0 = (const float*)d_in[2];
    const float* bi0 = (const float*)d_in[3];
    const float* gi0 = (const float*)d_in[4];
    const float* bei0= (const float*)d_in[5];
    const float* Wi1 = (const float*)d_in[6];
    const float* bi1 = (const float*)d_in[7];
    const float* gi1 = (const float*)d_in[8];
    const float* bei1= (const float*)d_in[9];
    const float* Wm  = (const float*)d_in[10];
    const float* bm  = (const float*)d_in[11];
    const float* gm  = (const float*)d_in[12];
    const float* bem = (const float*)d_in[13];
    const float* Wu  = (const float*)d_in[14];
    const float* bu  = (const float*)d_in[15];
    const float* gu  = (const float*)d_in[16];
    const float* beu = (const float*)d_in[17];
    const float* Wf0 = (const float*)d_in[18];
    const float* bf0 = (const float*)d_in[19];
    const float* Wf1 = (const float*)d_in[20];
    const float* bf1 = (const float*)d_in[21];
    const float* Wf2 = (const float*)d_in[22];
    const float* bf2 = (const float*)d_in[23];
    const float* Wf3 = (const float*)d_in[24];
    const float* bf3 = (const float*)d_in[25];
    const float* Wo  = (const float*)d_in[26];
    const float* bo  = (const float*)d_in[27];

    const int st_i0 = OFF_STATS;
    const int st_i1 = OFF_STATS + ST_STRIDE;
    const int st_m  = OFF_STATS + 2 * ST_STRIDE;    // + i*ST_STRIDE
    const int st_u  = OFF_STATS + 12 * ST_STRIDE;   // + i*ST_STRIDE

    const int RING[4] = { OFF_RING, OFF_RING + NV, OFF_RING + 2 * NV, OFF_RING + 3 * NV };

    dim3 blk(256);
    k_zero_v19<<<NBLK, blk, 0, stream>>>();
    k_bcnt_v19<<<NCBLK, blk, 0, stream>>>(col);
    k_bscan_v19<<<1, 512, 0, stream>>>();
    k_binfill_v19<<<NCBLK, blk, 0, stream>>>(col);
    k_csr_v19<<<NBKT, blk, 0, stream>>>();
    k_wprep_v18<<<200, blk, 0, stream>>>(Wf0, Wf1, Wf2, Wf3);

    // init MLP: x -> h0 (ring[0]); last k_nl chains layer-0 msg linear into bf16 MSGB
    k_init0_v17<<<1024, blk, 0, stream>>>(x, Wi0, bi0);
    k_nl_v17<<<1024, blk, 0, stream>>>(OFF_PA, OFF_PB, 0, st_i0, gi0, bei0, -1, -1, Wi1, bi1, st_i1);
    k_nl_v17<<<1024, blk, 0, stream>>>(OFF_PB, 0, 1, st_i1, gi1, bei1, -1, RING[0], Wm, bm, st_m);

    for (int i = 0; i < 10; ++i) {
        int h_cur = RING[i & 3];
        int h_new = RING[(i + 1) & 3];
        int resid = (i >= 2) ? RING[(i - 2) & 3] : -1;
        k_gather_v17<<<3125, blk, 0, stream>>>(st_m + i * ST_STRIDE, gm + i * 32, bem + i * 32);
        k_upd_v17<<<1024, blk, 0, stream>>>(h_cur, OFF_PB, Wu + i * 2048, bu + i * 32,
                                            st_u + i * ST_STRIDE);
        const float* Wn = (i < 9) ? (Wm + (i + 1) * 1024) : nullptr;
        const float* bn = (i < 9) ? (bm + (i + 1) * 32) : nullptr;
        int st_next = (i < 9) ? (st_m + (i + 1) * ST_STRIDE) : 0;
        k_nl_v17<<<1024, blk, 0, stream>>>(OFF_PB, 0, 1, st_u + i * ST_STRIDE,
                                           gu + i * 32, beu + i * 32,
                                           resid, h_new, Wn, bn, st_next);
    }

    k_final_v18<<<782, blk, 0, stream>>>(RING[2], bf0, bf1, bf2, bf3, Wo, bo, out);
}

// Round 4
// 966.833 us; speedup vs baseline: 1.3406x; 1.0118x over previous
//
#include <hip/hip_runtime.h>
#include <hip/hip_bf16.h>

#define NN 100000
#define NEDGE 1600000
#define NV (NN*32)
#define NEG 0.01f
#define EPS 1e-5f
#define NBLK 391            // ceil(NN/256)
#define NBKT 391            // ceil(NN/256) node buckets (256 nodes each)
#define CHUNK 4096          // edges per binning block
#define NCBLK 391           // ceil(NEDGE/CHUNK)
#define DCAP 6144           // LDS stage capacity in k_csr
#define STC 64              // stat copies (contention spread)
#define ST_STRIDE 4096      // STC * 64
#define NGBLK 1563          // ceil(NN/64) for fused gather+upd

// ---- static device arena (fp32) ----
#define OFF_STATS 0
#define STATS_F  (22*ST_STRIDE)
#define OFF_PA   STATS_F
#define OFF_PB   (OFF_PA + NV)
#define OFF_AGG  (OFF_PB + NV)
#define OFF_MSGB (OFF_AGG + NV)          // NV bf16 = NV/2 floats
#define OFF_RING (OFF_MSGB + NV/2)
#define OFF_WF   (OFF_RING + 4*NV)       // bf16 weight frags for final MLP (51200 shorts)
#define ARENA_F  (OFF_WF + 25600)

// weight-frag section bases in uint4 (16B) units
#define W0B 0
#define W1B 1024
#define W2B 5120
#define W3B 6144

__device__ __align__(16) float gA[ARENA_F];
__device__ int g_rowptr[NN + 1];
__device__ int g_csr[NEDGE];
__device__ int g_bin[NEDGE];       // bucket-grouped packed edges: (src<<8)|dlocal
__device__ int g_bcnt[NBKT];
__device__ int g_boff[NBKT];
__device__ int g_btail[NBKT];

__device__ __forceinline__ float lrelu(float v) { return v > 0.f ? v : v * NEG; }
__device__ __forceinline__ unsigned short f2b(float v) {
    __hip_bfloat16 b = __float2bfloat16(v);
    return *reinterpret_cast<unsigned short*>(&b);
}
__device__ __forceinline__ float b2f(unsigned short u) {
    __hip_bfloat16 b = *reinterpret_cast<__hip_bfloat16*>(&u);
    return __bfloat162float(b);
}

// ---------------- zero stats + bucket counts ----------------
__global__ void k_zero_v19()
{
    int i = blockIdx.x * 256 + threadIdx.x;
    if (i < STATS_F) gA[i] = 0.f;
    if (i < NBKT) g_bcnt[i] = 0;
}

// ---------------- bucket histogram (LDS-staged, low-contention) ----------------
__global__ __launch_bounds__(256) void k_bcnt_v19(const int* __restrict__ col)
{
    __shared__ int hist[NBKT];
    int tid = threadIdx.x;
    for (int b = tid; b < NBKT; b += 256) hist[b] = 0;
    __syncthreads();
    int e0 = blockIdx.x * CHUNK;
    #pragma unroll
    for (int r = 0; r < CHUNK / 256; ++r) {
        int e = e0 + r * 256 + tid;
        if (e < NEDGE) atomicAdd(&hist[col[NEDGE + e] >> 8], 1);
    }
    __syncthreads();
    for (int b = tid; b < NBKT; b += 256) {
        int v = hist[b];
        if (v) atomicAdd(&g_bcnt[b], v);
    }
}

// ---------------- scan bucket counts -> offsets + tails ----------------
__global__ __launch_bounds__(512) void k_bscan_v19()
{
    __shared__ int s[512];
    int t = threadIdx.x;
    int v = (t < NBKT) ? g_bcnt[t] : 0;
    s[t] = v;
    __syncthreads();
    for (int off = 1; off < 512; off <<= 1) {
        int u = (t >= off) ? s[t - off] : 0;
        __syncthreads();
        s[t] += u;
        __syncthreads();
    }
    if (t < NBKT) {
        int o = s[t] - v;
        g_boff[t] = o;
        g_btail[t] = o;
    }
}

// ---------------- bin edges into bucket-contiguous regions (chunked append) ----------------
__global__ __launch_bounds__(256) void k_binfill_v19(const int* __restrict__ col)
{
    __shared__ int ssrc[CHUNK];
    __shared__ int sdst[CHUNK];
    __shared__ int hist[NBKT];
    __shared__ int boffL[NBKT];
    __shared__ int cnt2[NBKT];
    int tid = threadIdx.x;
    for (int b = tid; b < NBKT; b += 256) { hist[b] = 0; cnt2[b] = 0; }
    __syncthreads();
    int e0 = blockIdx.x * CHUNK;
    #pragma unroll
    for (int r = 0; r < CHUNK / 256; ++r) {
        int i = r * 256 + tid;
        int e = e0 + i;
        if (e < NEDGE) {
            int s = col[e];
            int d = col[NEDGE + e];
            ssrc[i] = s;
            sdst[i] = d;
            atomicAdd(&hist[d >> 8], 1);
        }
    }
    __syncthreads();
    for (int b = tid; b < NBKT; b += 256) {
        int h = hist[b];
        if (h) boffL[b] = atomicAdd(&g_btail[b], h);
    }
    __syncthreads();
    #pragma unroll
    for (int r = 0; r < CHUNK / 256; ++r) {
        int i = r * 256 + tid;
        int e = e0 + i;
        if (e < NEDGE) {
            int d = sdst[i];
            int b = d >> 8;
            int rk = atomicAdd(&cnt2[b], 1);
            g_bin[boffL[b] + rk] = (ssrc[i] << 8) | (d & 255);
        }
    }
}

// ---------------- per-bucket local sort -> exact CSR (coalesced block-local writes) ----------------
__global__ __launch_bounds__(256) void k_csr_v19()
{
    __shared__ int stg[DCAP];
    __shared__ int c1[256];
    __shared__ int sc[256];
    __shared__ int sl[256];
    __shared__ int c2[256];
    int tid = threadIdx.x, b = blockIdx.x;
    int base = g_boff[b];
    int cntE = g_bcnt[b];
    c1[tid] = 0; c2[tid] = 0;
    __syncthreads();
    for (int i = tid; i < cntE; i += 256) {
        int p = g_bin[base + i];
        if (i < DCAP) stg[i] = p;
        atomicAdd(&c1[p & 255], 1);
    }
    __syncthreads();
    int v = c1[tid];
    sc[tid] = v;
    __syncthreads();
    for (int off = 1; off < 256; off <<= 1) {
        int u = (tid >= off) ? sc[tid - off] : 0;
        __syncthreads();
        sc[tid] += u;
        __syncthreads();
    }
    int loff = sc[tid] - v;
    sl[tid] = loff;
    int node = b * 256 + tid;
    if (node < NN) g_rowptr[node] = base + loff;
    if (b == NBKT - 1 && tid == 0) g_rowptr[NN] = NEDGE;
    __syncthreads();
    for (int i = tid; i < cntE; i += 256) {
        int p = (i < DCAP) ? stg[i] : g_bin[base + i];
        int dl = p & 255;
        int rk = atomicAdd(&c2[dl], 1);
        g_csr[base + sl[dl] + rk] = p >> 8;
    }
}

// ---------------- init layer 0: PA = x*Wi0 + bi0, stats ----------------
__global__ void k_init0_v17(const float* __restrict__ x, const float* __restrict__ Wi0,
                            const float* __restrict__ bi0)
{
    int j = threadIdx.x & 31, ns = threadIdx.x >> 5;
    float w = Wi0[j];
    float bb = bi0[j];
    __shared__ float red[64];
    if (threadIdx.x < 64) red[threadIdx.x] = 0.f;
    __syncthreads();
    float s1 = 0.f, s2 = 0.f;
    for (int t = blockIdx.x; t < NN / 8; t += gridDim.x) {
        int n = t * 8 + ns;
        float v = x[n] * w + bb;
        gA[OFF_PA + n * 32 + j] = v;
        s1 += v; s2 += v * v;
    }
    atomicAdd(&red[j], s1);
    atomicAdd(&red[j + 32], s2);
    __syncthreads();
    if (threadIdx.x < 64)
        atomicAdd(&gA[OFF_STATS + (blockIdx.x & (STC - 1)) * 64 + threadIdx.x], red[threadIdx.x]);
}

// ------- BN+LReLU (+resid) (+feats store) (+fused next 32x32 linear + stats) -------
__global__ void k_nl_v17(int off_in, int off_out, int out_msg, int st_in,
                         const float* __restrict__ gamma, const float* __restrict__ beta,
                         int off_resid, int off_feats,
                         const float* __restrict__ Wn, const float* __restrict__ bn,
                         int st_out)
{
    int j = threadIdx.x & 31, ns = threadIdx.x >> 5;
    __shared__ float sstat[64];
    __shared__ float red[64];
    if (threadIdx.x < 64) {
        red[threadIdx.x] = 0.f;
        float acc = 0.f;
        int base = st_in + threadIdx.x;
        #pragma unroll 8
        for (int c = 0; c < STC; ++c) acc += gA[base + c * 64];
        sstat[threadIdx.x] = acc;
    }
    __syncthreads();
    float mean = sstat[j] * (1.f / NN);
    float var  = sstat[32 + j] * (1.f / NN) - mean * mean;
    float scale = gamma[j] * rsqrtf(var + EPS);
    float shift = beta[j] - mean * scale;

    float wc[32]; float bb = 0.f;
    if (Wn) {
        #pragma unroll
        for (int k = 0; k < 32; ++k) wc[k] = Wn[k * 32 + j];
        bb = bn[j];
    }
    unsigned short* mb = (unsigned short*)(gA + OFF_MSGB);
    __shared__ float sH[8][32];
    float s1 = 0.f, s2 = 0.f;
    for (int t = blockIdx.x; t < NN / 8; t += gridDim.x) {
        int n = t * 8 + ns;
        float v = gA[off_in + n * 32 + j];
        v = lrelu(scale * v + shift);
        if (off_resid >= 0) v += gA[off_resid + n * 32 + j];
        if (off_feats >= 0) gA[off_feats + n * 32 + j] = v;
        if (Wn) {
            sH[ns][j] = v;
            __syncthreads();
            float acc = bb;
            #pragma unroll
            for (int k = 0; k < 32; k += 4) {
                float4 h4 = *(const float4*)&sH[ns][k];
                acc += h4.x * wc[k] + h4.y * wc[k + 1] + h4.z * wc[k + 2] + h4.w * wc[k + 3];
            }
            if (out_msg) mb[n * 32 + j] = f2b(acc);
            else gA[off_out + n * 32 + j] = acc;
            s1 += acc; s2 += acc * acc;
            __syncthreads();
        }
    }
    if (Wn) {
        atomicAdd(&red[j], s1);
        atomicAdd(&red[j + 32], s2);
        __syncthreads();
        if (threadIdx.x < 64)
            atomicAdd(&gA[st_out + (blockIdx.x & (STC - 1)) * 64 + threadIdx.x], red[threadIdx.x]);
    }
}

// ======== fused gather (msg BN+LReLU, CSR segment-sum) + update GEMM ========
// Phase A: 4 lanes/node, 16B uint4 loads of bf16 msg rows (halves vmem instrs
//          vs 8x8B), fp32 accumulate -> LDS sAgg (order per feature identical
//          to v17/v19: ascending e, so numerics are bitwise unchanged).
// Phase B: PB = [h, agg] @ Wu + bu from LDS (no AGG global round-trip), stats.
__global__ __launch_bounds__(256) void k_gupd_v20(int st_msg,
                                                  const float* __restrict__ gm,
                                                  const float* __restrict__ bem,
                                                  int off_h,
                                                  const float* __restrict__ Wu_i,
                                                  const float* __restrict__ bu_i,
                                                  int st_out)
{
    __shared__ float sstat[64];
    __shared__ float scl[32], shf[32];
    __shared__ float sH[64][36];
    __shared__ float sAgg[64][36];
    __shared__ float red[64];
    int tid = threadIdx.x;
    int nb = blockIdx.x * 64;

    if (tid < 64) {
        red[tid] = 0.f;
        float acc = 0.f;
        int base = st_msg + tid;
        #pragma unroll 8
        for (int c = 0; c < STC; ++c) acc += gA[base + c * 64];
        sstat[tid] = acc;
    }
    // stage h rows (64 x 32) while stats settle
    {
        const float* hp = gA + off_h + nb * 32;
        int lim = min(2048, (NN - nb) * 32);
        for (int idx = tid; idx < lim; idx += 256)
            sH[idx >> 5][idx & 31] = hp[idx];
    }
    __syncthreads();
    if (tid < 32) {
        float mean = sstat[tid] * (1.f / NN);
        float var  = sstat[32 + tid] * (1.f / NN) - mean * mean;
        float s = gm[tid] * rsqrtf(var + EPS);
        scl[tid] = s;
        shf[tid] = bem[tid] - mean * s;
    }
    __syncthreads();

    // ---- phase A: gather ----
    {
        int nl = tid >> 2;          // local node 0..63
        int g  = tid & 3;           // feature group (8 feats)
        int n  = nb + nl;
        float c[8], h[8];
        #pragma unroll
        for (int q = 0; q < 8; ++q) { c[q] = scl[g * 8 + q]; h[q] = shf[g * 8 + q]; }
        float a[8];
        #pragma unroll
        for (int q = 0; q < 8; ++q) a[q] = 0.f;
        if (n < NN) {
            const unsigned short* mb = (const unsigned short*)(gA + OFF_MSGB);
            int e0 = g_rowptr[n], e1 = g_rowptr[n + 1];
            int e = e0;
            for (; e + 3 < e1; e += 4) {
                int s0 = g_csr[e];
                int s1 = g_csr[e + 1];
                int s2 = g_csr[e + 2];
                int s3 = g_csr[e + 3];
                uint4 m0 = *(const uint4*)(mb + (s0 << 5) + (g << 3));
                uint4 m1 = *(const uint4*)(mb + (s1 << 5) + (g << 3));
                uint4 m2 = *(const uint4*)(mb + (s2 << 5) + (g << 3));
                uint4 m3 = *(const uint4*)(mb + (s3 << 5) + (g << 3));
                #pragma unroll
                for (int w = 0; w < 4; ++w) {
                    unsigned int u0 = (&m0.x)[w], u1 = (&m1.x)[w], u2 = (&m2.x)[w], u3 = (&m3.x)[w];
                    int q = w * 2;
                    a[q]   += lrelu(c[q]   * b2f((unsigned short)(u0 & 0xffff)) + h[q])
                            + lrelu(c[q]   * b2f((unsigned short)(u1 & 0xffff)) + h[q])
                            + lrelu(c[q]   * b2f((unsigned short)(u2 & 0xffff)) + h[q])
                            + lrelu(c[q]   * b2f((unsigned short)(u3 & 0xffff)) + h[q]);
                    a[q+1] += lrelu(c[q+1] * b2f((unsigned short)(u0 >> 16)) + h[q+1])
                            + lrelu(c[q+1] * b2f((unsigned short)(u1 >> 16)) + h[q+1])
                            + lrelu(c[q+1] * b2f((unsigned short)(u2 >> 16)) + h[q+1])
                            + lrelu(c[q+1] * b2f((unsigned short)(u3 >> 16)) + h[q+1]);
                }
            }
            for (; e < e1; ++e) {
                int s0 = g_csr[e];
                uint4 m0 = *(const uint4*)(mb + (s0 << 5) + (g << 3));
                #pragma unroll
                for (int w = 0; w < 4; ++w) {
                    unsigned int u0 = (&m0.x)[w];
                    int q = w * 2;
                    a[q]   += lrelu(c[q]   * b2f((unsigned short)(u0 & 0xffff)) + h[q]);
                    a[q+1] += lrelu(c[q+1] * b2f((unsigned short)(u0 >> 16)) + h[q+1]);
                }
            }
        }
        *(float4*)&sAgg[nl][g * 8]     = make_float4(a[0], a[1], a[2], a[3]);
        *(float4*)&sAgg[nl][g * 8 + 4] = make_float4(a[4], a[5], a[6], a[7]);
    }
    __syncthreads();

    // ---- phase B: update GEMM ----
    {
        int j = tid & 31, ns = tid >> 5;
        float wc[64];
        #pragma unroll
        for (int k = 0; k < 64; ++k) wc[k] = Wu_i[k * 32 + j];
        float bb = bu_i[j];
        float s1 = 0.f, s2 = 0.f;
        #pragma unroll
        for (int it = 0; it < 8; ++it) {
            int nl = it * 8 + ns;
            int n = nb + nl;
            if (n >= NN) break;
            float acc = bb;
            #pragma unroll
            for (int k = 0; k < 32; k += 4) {
                float4 h4 = *(const float4*)&sH[nl][k];
                acc += h4.x * wc[k] + h4.y * wc[k + 1] + h4.z * wc[k + 2] + h4.w * wc[k + 3];
                float4 a4 = *(const float4*)&sAgg[nl][k];
                acc += a4.x * wc[32 + k] + a4.y * wc[32 + k + 1] + a4.z * wc[32 + k + 2] + a4.w * wc[32 + k + 3];
            }
            gA[OFF_PB + n * 32 + j] = acc;
            s1 += acc; s2 += acc * acc;
        }
        atomicAdd(&red[j], s1);
        atomicAdd(&red[j + 32], s2);
        __syncthreads();
        if (tid < 64)
            atomicAdd(&gA[st_out + (blockIdx.x & (STC - 1)) * 64 + tid], red[tid]);
    }
}

// ================= MFMA final MLP =================
typedef __attribute__((ext_vector_type(8))) short bf16x8;
typedef __attribute__((ext_vector_type(4))) float f32x4;

union FC { uint4 u; bf16x8 b; };

#define MFMA(a, b, c) __builtin_amdgcn_mfma_f32_16x16x32_bf16(a, b, c, 0, 0, 0)

__device__ __forceinline__ bf16x8 ld_wf(const uint4* p) {
    FC c; c.u = *p; return c.b;
}

__device__ __forceinline__ f32x4 ld_bias4(const float* p) {
    float4 t = *(const float4*)p;
    f32x4 r; r[0] = t.x; r[1] = t.y; r[2] = t.z; r[3] = t.w; return r;
}

__device__ __forceinline__ f32x4 lrelu4(f32x4 v) {
    f32x4 r;
    #pragma unroll
    for (int k = 0; k < 4; ++k) r[k] = v[k] > 0.f ? v[k] : v[k] * NEG;
    return r;
}

__device__ __forceinline__ void splitpack(const float* v, bf16x8& hi, bf16x8& lo) {
    unsigned int h[4], l[4];
    #pragma unroll
    for (int k = 0; k < 4; ++k) {
        unsigned short h0 = f2b(v[2*k]), h1 = f2b(v[2*k+1]);
        float r0 = v[2*k]   - b2f(h0);
        float r1 = v[2*k+1] - b2f(h1);
        h[k] = (unsigned int)h0 | ((unsigned int)h1 << 16);
        l[k] = (unsigned int)f2b(r0) | ((unsigned int)f2b(r1) << 16);
    }
    FC ch; ch.u = make_uint4(h[0], h[1], h[2], h[3]); hi = ch.b;
    FC cl; cl.u = make_uint4(l[0], l[1], l[2], l[3]); lo = cl.b;
}

__global__ __launch_bounds__(256) void k_wprep_v18(const float* __restrict__ W0,
                                                   const float* __restrict__ W1,
                                                   const float* __restrict__ W2,
                                                   const float* __restrict__ W3)
{
    int i = blockIdx.x * 256 + threadIdx.x;
    if (i >= 51200) return;
    const float* src; int Nout, nk; int r = i;
    if (r < 8192)       { src = W0; Nout = 256; nk = 1; }
    else if (r < 40960) { src = W1; Nout = 128; nk = 8; r -= 8192; }
    else if (r < 49152) { src = W2; Nout = 64;  nk = 4; r -= 40960; }
    else                { src = W3; Nout = 32;  nk = 2; r -= 49152; }
    int frag = r >> 9;
    int lane = (r >> 3) & 63;
    int j = r & 7;
    int T = frag / nk, s = frag - T * nk;
    int g = lane >> 4;
    int outf = T * 16 + (lane & 15);
    int inf = 32 * s + 16 * (j >> 2) + 4 * g + (j & 3);
    unsigned short* dst = (unsigned short*)(gA + OFF_WF);
    dst[i] = f2b(src[inf * Nout + outf]);
}

__global__ __launch_bounds__(256) void k_final_v18(
    int off_h,
    const float* __restrict__ bf0, const float* __restrict__ bf1,
    const float* __restrict__ bf2, const float* __restrict__ bf3,
    const float* __restrict__ Wo,  const float* __restrict__ bo,
    float* __restrict__ out)
{
    int lane = threadIdx.x & 63;
    int wave = threadIdx.x >> 6;
    int c = lane & 15;
    int g = lane >> 4;
    int nb = blockIdx.x * 128 + wave * 32;
    int n0 = nb + c;
    int n1 = nb + 16 + c;
    int ld0 = min(n0, NN - 1), ld1 = min(n1, NN - 1);

    const float* h = gA + off_h;
    const uint4* WF = (const uint4*)(gA + OFF_WF);

    float4 ia0 = *(const float4*)&h[ld0 * 32 + 4 * g];
    float4 ib0 = *(const float4*)&h[ld0 * 32 + 16 + 4 * g];
    float4 ia1 = *(const float4*)&h[ld1 * 32 + 4 * g];
    float4 ib1 = *(const float4*)&h[ld1 * 32 + 16 + 4 * g];
    bf16x8 Bh0, Bl0, Bh1, Bl1;
    {
        float v0[8] = {ia0.x, ia0.y, ia0.z, ia0.w, ib0.x, ib0.y, ib0.z, ib0.w};
        float v1[8] = {ia1.x, ia1.y, ia1.z, ia1.w, ib1.x, ib1.y, ib1.z, ib1.w};
        splitpack(v0, Bh0, Bl0);
        splitpack(v1, Bh1, Bl1);
    }

    f32x4 A0[16][2];
    #pragma unroll
    for (int t = 0; t < 16; ++t) {
        f32x4 ci = ld_bias4(bf0 + t * 16 + 4 * g);
        bf16x8 w = ld_wf(WF + W0B + t * 64 + lane);
        f32x4 d0 = MFMA(w, Bh0, ci);
        d0 = MFMA(w, Bl0, d0);
        f32x4 d1 = MFMA(w, Bh1, ci);
        d1 = MFMA(w, Bl1, d1);
        A0[t][0] = lrelu4(d0);
        A0[t][1] = lrelu4(d1);
    }

    f32x4 A1[8][2];
    #pragma unroll
    for (int T = 0; T < 8; ++T) {
        f32x4 ci = ld_bias4(bf1 + T * 16 + 4 * g);
        A1[T][0] = ci; A1[T][1] = ci;
    }
    #pragma unroll
    for (int s = 0; s < 8; ++s) {
        bf16x8 bh[2], bl[2];
        #pragma unroll
        for (int u = 0; u < 2; ++u) {
            float vv[8] = {A0[2*s][u][0], A0[2*s][u][1], A0[2*s][u][2], A0[2*s][u][3],
                           A0[2*s+1][u][0], A0[2*s+1][u][1], A0[2*s+1][u][2], A0[2*s+1][u][3]};
            splitpack(vv, bh[u], bl[u]);
        }
        #pragma unroll
        for (int T = 0; T < 8; ++T) {
            bf16x8 w = ld_wf(WF + W1B + (T * 8 + s) * 64 + lane);
            A1[T][0] = MFMA(w, bh[0], A1[T][0]);
            A1[T][0] = MFMA(w, bl[0], A1[T][0]);
            A1[T][1] = MFMA(w, bh[1], A1[T][1]);
            A1[T][1] = MFMA(w, bl[1], A1[T][1]);
        }
    }
    #pragma unroll
    for (int T = 0; T < 8; ++T) { A1[T][0] = lrelu4(A1[T][0]); A1[T][1] = lrelu4(A1[T][1]); }

    f32x4 A2[4][2];
    #pragma unroll
    for (int T = 0; T < 4; ++T) {
        f32x4 ci = ld_bias4(bf2 + T * 16 + 4 * g);
        A2[T][0] = ci; A2[T][1] = ci;
    }
    #pragma unroll
    for (int s = 0; s < 4; ++s) {
        bf16x8 bh[2], bl[2];
        #pragma unroll
        for (int u = 0; u < 2; ++u) {
            float vv[8] = {A1[2*s][u][0], A1[2*s][u][1], A1[2*s][u][2], A1[2*s][u][3],
                           A1[2*s+1][u][0], A1[2*s+1][u][1], A1[2*s+1][u][2], A1[2*s+1][u][3]};
            splitpack(vv, bh[u], bl[u]);
        }
        #pragma unroll
        for (int T = 0; T < 4; ++T) {
            bf16x8 w = ld_wf(WF + W2B + (T * 4 + s) * 64 + lane);
            A2[T][0] = MFMA(w, bh[0], A2[T][0]);
            A2[T][0] = MFMA(w, bl[0], A2[T][0]);
            A2[T][1] = MFMA(w, bh[1], A2[T][1]);
            A2[T][1] = MFMA(w, bl[1], A2[T][1]);
        }
    }
    #pragma unroll
    for (int T = 0; T < 4; ++T) { A2[T][0] = lrelu4(A2[T][0]); A2[T][1] = lrelu4(A2[T][1]); }

    f32x4 A3[2][2];
    #pragma unroll
    for (int T = 0; T < 2; ++T) {
        f32x4 ci = ld_bias4(bf3 + T * 16 + 4 * g);
        A3[T][0] = ci; A3[T][1] = ci;
    }
    #pragma unroll
    for (int s = 0; s < 2; ++s) {
        bf16x8 bh[2], bl[2];
        #pragma unroll
        for (int u = 0; u < 2; ++u) {
            float vv[8] = {A2[2*s][u][0], A2[2*s][u][1], A2[2*s][u][2], A2[2*s][u][3],
                           A2[2*s+1][u][0], A2[2*s+1][u][1], A2[2*s+1][u][2], A2[2*s+1][u][3]};
            splitpack(vv, bh[u], bl[u]);
        }
        #pragma unroll
        for (int T = 0; T < 2; ++T) {
            bf16x8 w = ld_wf(WF + W3B + (T * 2 + s) * 64 + lane);
            A3[T][0] = MFMA(w, bh[0], A3[T][0]);
            A3[T][0] = MFMA(w, bl[0], A3[T][0]);
            A3[T][1] = MFMA(w, bh[1], A3[T][1]);
            A3[T][1] = MFMA(w, bl[1], A3[T][1]);
        }
    }
    #pragma unroll
    for (int T = 0; T < 2; ++T) { A3[T][0] = lrelu4(A3[T][0]); A3[T][1] = lrelu4(A3[T][1]); }

    float4 woa = *(const float4*)&Wo[4 * g];
    float4 wob = *(const float4*)&Wo[16 + 4 * g];
    float z0 = A3[0][0][0]*woa.x + A3[0][0][1]*woa.y + A3[0][0][2]*woa.z + A3[0][0][3]*woa.w
             + A3[1][0][0]*wob.x + A3[1][0][1]*wob.y + A3[1][0][2]*wob.z + A3[1][0][3]*wob.w;
    float z1 = A3[0][1][0]*woa.x + A3[0][1][1]*woa.y + A3[0][1][2]*woa.z + A3[0][1][3]*woa.w
             + A3[1][1][0]*wob.x + A3[1][1][1]*wob.y + A3[1][1][2]*wob.z + A3[1][1][3]*wob.w;
    z0 += __shfl_xor(z0, 16); z0 += __shfl_xor(z0, 32);
    z1 += __shfl_xor(z1, 16); z1 += __shfl_xor(z1, 32);
    float bb = bo[0];
    if (g == 0 && n0 < NN) out[n0] = 1.f / (1.f + __expf(-(z0 + bb)));
    if (g == 1 && n1 < NN) out[n1] = 1.f / (1.f + __expf(-(z1 + bb)));
}

extern "C" void kernel_launch(void* const* d_in, const int* in_sizes, int n_in,
                              void* d_out, int out_size, void* d_ws, size_t ws_size,
                              hipStream_t stream)
{
    (void)in_sizes; (void)n_in; (void)out_size; (void)d_ws; (void)ws_size;
    float* out = (float*)d_out;

    const float* x   = (const float*)d_in[0];
    const int*  col  = (const int*) d_in[1];
    const float* Wi0 = (const float*)d_in[2];
    const float* bi0 = (const float*)d_in[3];
    const float* gi0 = (const float*)d_in[4];
    const float* bei0= (const float*)d_in[5];
    const float* Wi1 = (const float*)d_in[6];
    const float* bi1 = (const float*)d_in[7];
    const float* gi1 = (const float*)d_in[8];
    const float* bei1= (const float*)d_in[9];
    const float* Wm  = (const float*)d_in[10];
    const float* bm  = (const float*)d_in[11];
    const float* gm  = (const float*)d_in[12];
    const float* bem = (const float*)d_in[13];
    const float* Wu  = (const float*)d_in[14];
    const float* bu  = (const float*)d_in[15];
    const float* gu  = (const float*)d_in[16];
    const float* beu = (const float*)d_in[17];
    const float* Wf0 = (const float*)d_in[18];
    const float* bf0 = (const float*)d_in[19];
    const float* Wf1 = (const float*)d_in[20];
    const float* bf1 = (const float*)d_in[21];
    const float* Wf2 = (const float*)d_in[22];
    const float* bf2 = (const float*)d_in[23];
    const float* Wf3 = (const float*)d_in[24];
    const float* bf3 = (const float*)d_in[25];
    const float* Wo  = (const float*)d_in[26];
    const float* bo  = (const float*)d_in[27];

    const int st_i0 = OFF_STATS;
    const int st_i1 = OFF_STATS + ST_STRIDE;
    const int st_m  = OFF_STATS + 2 * ST_STRIDE;    // + i*ST_STRIDE
    const int st_u  = OFF_STATS + 12 * ST_STRIDE;   // + i*ST_STRIDE

    const int RING[4] = { OFF_RING, OFF_RING + NV, OFF_RING + 2 * NV, OFF_RING + 3 * NV };

    dim3 blk(256);
    k_zero_v19<<<NBLK, blk, 0, stream>>>();
    k_bcnt_v19<<<NCBLK, blk, 0, stream>>>(col);
    k_bscan_v19<<<1, 512, 0, stream>>>();
    k_binfill_v19<<<NCBLK, blk, 0, stream>>>(col);
    k_csr_v19<<<NBKT, blk, 0, stream>>>();
    k_wprep_v18<<<200, blk, 0, stream>>>(Wf0, Wf1, Wf2, Wf3);

    // init MLP: x -> h0 (ring[0]); last k_nl chains layer-0 msg linear into bf16 MSGB
    k_init0_v17<<<1024, blk, 0, stream>>>(x, Wi0, bi0);
    k_nl_v17<<<1024, blk, 0, stream>>>(OFF_PA, OFF_PB, 0, st_i0, gi0, bei0, -1, -1, Wi1, bi1, st_i1);
    k_nl_v17<<<1024, blk, 0, stream>>>(OFF_PB, 0, 1, st_i1, gi1, bei1, -1, RING[0], Wm, bm, st_m);

    for (int i = 0; i < 10; ++i) {
        int h_cur = RING[i & 3];
        int h_new = RING[(i + 1) & 3];
        int resid = (i >= 2) ? RING[(i - 2) & 3] : -1;
        k_gupd_v20<<<NGBLK, blk, 0, stream>>>(st_m + i * ST_STRIDE, gm + i * 32, bem + i * 32,
                                              h_cur, Wu + i * 2048, bu + i * 32,
                                              st_u + i * ST_STRIDE);
        const float* Wn = (i < 9) ? (Wm + (i + 1) * 1024) : nullptr;
        const float* bn = (i < 9) ? (bm + (i + 1) * 32) : nullptr;
        int st_next = (i < 9) ? (st_m + (i + 1) * ST_STRIDE) : 0;
        k_nl_v17<<<1024, blk, 0, stream>>>(OFF_PB, 0, 1, st_u + i * ST_STRIDE,
                                           gu + i * 32, beu + i * 32,
                                           resid, h_new, Wn, bn, st_next);
    }

    k_final_v18<<<782, blk, 0, stream>>>(RING[2], bf0, bf1, bf2, bf3, Wo, bo, out);
}